// Round 3
// baseline (32.304 us; speedup 1.0000x reference)
//
#include <hip/hip_runtime.h>

// Shapley fusion: L=5 views, C=64 channels, N=128*256 spatial positions.
// f(subset) = relu(b + sum_{l in subset} d[l]) where d[l] = dot(feats[l,:,n], w)
// -- the reference's [M,N,C] subset GEMM collapses to 5 dots per pixel.
// Shapley coef for L=5 by subset size: {-, -0.6, 0.05, 1/30, 0.05, 0.2}.
//
// Round-3 geometry: 2048 blocks x 128 threads (2 waves). Block covers 16
// consecutive n; wave h covers channels h*32..h*32+31 (2 ch/thread). Partial
// dots reduced by butterfly within the wave, then across the two waves via
// 640 B of LDS (one barrier). Phase C re-reads feats (L2/L3-hot). VGPR held
// <=128 via launch_bounds -> 4096 waves at 4 waves/SIMD (2x round-2 depth).

constexpr int L_VIEWS = 5;
constexpr int C_CH    = 64;
constexpr int NPIX    = 128 * 256;   // 32768

__global__ __launch_bounds__(128, 4)
void shapley_fusion_kernel(const float* __restrict__ feats,
                           const float* __restrict__ w,
                           const float* __restrict__ bptr,
                           float* __restrict__ out)
{
    const int tid  = threadIdx.x;
    const int h    = tid >> 6;        // wave in block: channel half (0/1)
    const int lane = tid & 63;
    const int n4l  = lane & 3;        // n quad within the 16-n window
    const int cg   = lane >> 2;       // channel group (0..15) within half
    const int n    = blockIdx.x * 16 + n4l * 4;
    const int c0   = h * 32 + cg * 2; // this thread's 2 channels

    const float w0   = w[c0];
    const float w1   = w[c0 + 1];
    const float bias = bptr[0];

    // ---- Phase A: issue all 10 loads, stream into partial dots. ----
    float4 va[L_VIEWS][2];
#pragma unroll
    for (int l = 0; l < L_VIEWS; ++l)
#pragma unroll
        for (int cc = 0; cc < 2; ++cc)
            va[l][cc] = *reinterpret_cast<const float4*>(
                feats + ((size_t)(l * C_CH + c0 + cc) * NPIX + n));

    float d[L_VIEWS][4];
#pragma unroll
    for (int l = 0; l < L_VIEWS; ++l) {
        d[l][0] = va[l][0].x * w0 + va[l][1].x * w1;
        d[l][1] = va[l][0].y * w0 + va[l][1].y * w1;
        d[l][2] = va[l][0].z * w0 + va[l][1].z * w1;
        d[l][3] = va[l][0].w * w0 + va[l][1].w * w1;
    }

    // Butterfly reduce across the 16 channel-groups (lane bits 2..5).
#pragma unroll
    for (int l = 0; l < L_VIEWS; ++l) {
#pragma unroll
        for (int j = 0; j < 4; ++j) {
            d[l][j] += __shfl_xor(d[l][j], 4, 64);
            d[l][j] += __shfl_xor(d[l][j], 8, 64);
            d[l][j] += __shfl_xor(d[l][j], 16, 64);
            d[l][j] += __shfl_xor(d[l][j], 32, 64);
        }
    }

    // ---- Cross-wave reduce: exchange the two channel-halves via LDS. ----
    __shared__ float xl[2 * 4 * L_VIEWS * 4];   // [half][quad][l][j]
    if (cg == 0) {
#pragma unroll
        for (int l = 0; l < L_VIEWS; ++l)
#pragma unroll
            for (int j = 0; j < 4; ++j)
                xl[((h * 4 + n4l) * L_VIEWS + l) * 4 + j] = d[l][j];
    }
    __syncthreads();
#pragma unroll
    for (int l = 0; l < L_VIEWS; ++l)
#pragma unroll
        for (int j = 0; j < 4; ++j)
            d[l][j] += xl[(((1 - h) * 4 + n4l) * L_VIEWS + l) * 4 + j];

    // ---- Phase B: subset lattice -> shapley -> softmax (per n sub-index). ----
    constexpr float WT1 = -0.6f;          // singleton: -(L-2)/L
    constexpr float WT2 = 0.05f;          // 1!*3!/5!
    constexpr float WT3 = 1.0f / 30.0f;   // 2!*2!/5!
    constexpr float WT4 = 0.05f;          // 3!*1!/5!
    constexpr float WT5 = 0.2f;           // 4!*0!/5!

    float attn[L_VIEWS][4];
#pragma unroll
    for (int j = 0; j < 4; ++j) {
        float s[32];
        s[0] = bias;                      // fold bias into the lattice root
        float sh[L_VIEWS] = {0.f, 0.f, 0.f, 0.f, 0.f};
#pragma unroll
        for (int m = 1; m < 32; ++m) {
            const int lb  = m & (-m);
            const int lbi = __builtin_ctz(m);
            s[m] = s[m ^ lb] + d[lbi][j];
            const float f = fmaxf(s[m], 0.f);
            const int pc = __builtin_popcount(m);
            const float wt = (pc == 1) ? WT1 : (pc == 2) ? WT2
                           : (pc == 3) ? WT3 : (pc == 4) ? WT4 : WT5;
#pragma unroll
            for (int i = 0; i < L_VIEWS; ++i)
                if (m & (1 << i)) sh[i] += wt * f;
        }
        float mx = sh[0];
#pragma unroll
        for (int i = 1; i < L_VIEWS; ++i) mx = fmaxf(mx, sh[i]);
        float e[L_VIEWS];
        float sum = 0.f;
#pragma unroll
        for (int i = 0; i < L_VIEWS; ++i) { e[i] = __expf(sh[i] - mx); sum += e[i]; }
        const float inv = __fdividef(1.f, sum);
#pragma unroll
        for (int i = 0; i < L_VIEWS; ++i) attn[i][j] = e[i] * inv;
    }

    // ---- Phase C: re-read feats (L2/L3-hot) and emit fused output. ----
    float4 vc[L_VIEWS][2];
#pragma unroll
    for (int l = 0; l < L_VIEWS; ++l)
#pragma unroll
        for (int cc = 0; cc < 2; ++cc)
            vc[l][cc] = *reinterpret_cast<const float4*>(
                feats + ((size_t)(l * C_CH + c0 + cc) * NPIX + n));

#pragma unroll
    for (int cc = 0; cc < 2; ++cc) {
        float4 acc;
        acc.x = vc[0][cc].x * attn[0][0];
        acc.y = vc[0][cc].y * attn[0][1];
        acc.z = vc[0][cc].z * attn[0][2];
        acc.w = vc[0][cc].w * attn[0][3];
#pragma unroll
        for (int l = 1; l < L_VIEWS; ++l) {
            acc.x += vc[l][cc].x * attn[l][0];
            acc.y += vc[l][cc].y * attn[l][1];
            acc.z += vc[l][cc].z * attn[l][2];
            acc.w += vc[l][cc].w * attn[l][3];
        }
        *reinterpret_cast<float4*>(out + (size_t)(c0 + cc) * NPIX + n) = acc;
    }
}

extern "C" void kernel_launch(void* const* d_in, const int* in_sizes, int n_in,
                              void* d_out, int out_size, void* d_ws, size_t ws_size,
                              hipStream_t stream) {
    const float* feats = (const float*)d_in[0];   // [5,64,128,256] fp32
    const float* w     = (const float*)d_in[1];   // [64,1] fp32
    const float* b     = (const float*)d_in[2];   // [1] fp32
    float* out         = (float*)d_out;           // [64,128,256] fp32

    // 2048 blocks x 128 threads = 4096 waves; each block owns 16 consecutive n.
    shapley_fusion_kernel<<<NPIX / 16, 128, 0, stream>>>(feats, w, b, out);
}

// Round 4
// 15.655 us; speedup vs baseline: 2.0635x; 2.0635x over previous
//
#include <hip/hip_runtime.h>

// Shapley fusion: L=5 views, C=64 channels, N=128*256 spatial positions.
// f(subset) = relu(b + sum_{l in subset} d[l]) where d[l] = dot(feats[l,:,n], w)
// -- the reference's [M,N,C] subset GEMM collapses to 5 dots per pixel.
// Shapley coef for L=5 by subset size: {-, -0.6, 0.05, 1/30, 0.05, 0.2}.
//
// Round-4 geometry: 1024 blocks x 256 threads (4 waves); block owns a 32-n
// window (= exactly one 128-B line per row -- line-aligned, no cross-block
// line splits; round-3's 64-B windows caused 2x line over-fetch).
// Lane = q(0..7: n-quad) + 8*g(0..7: channel group); wave h owns channels
// {h*8+g, h*8+g+32}. Every global load/store instruction touches 8 rows x
// 128 B FULL lines (vs round-2's 16 x 64-B segments). feats kept in regs
// (10 float4/thread) -> read exactly once. Phase B computed once per (q,j)
// with j=g&3 (4x less redundancy), attn redistributed by one shuffle round.

constexpr int L_VIEWS = 5;
constexpr int C_CH    = 64;
constexpr int NPIX    = 128 * 256;   // 32768

__global__ __launch_bounds__(256)
void shapley_fusion_kernel(const float* __restrict__ feats,
                           const float* __restrict__ w,
                           const float* __restrict__ bptr,
                           float* __restrict__ out)
{
    const int tid  = threadIdx.x;
    const int h    = tid >> 6;         // wave in block (0..3): channel quarter
    const int lane = tid & 63;
    const int q    = lane & 7;         // n-quad within the 32-n window
    const int g    = (lane >> 3) & 7;  // channel group within wave
    const int win  = blockIdx.x * 32;  // 128-B aligned n window
    const int nq   = win + q * 4;
    const int cA   = h * 8 + g;        // this thread's 2 channels
    const int cB   = cA + 32;

    const float w0   = w[cA];
    const float w1   = w[cB];
    const float bias = bptr[0];

    // ---- Phase A: load 10 float4s (held in regs through the whole kernel).
    // Per instruction: lanes q=0..7 cover 128 B contiguous, g=0..7 covers 8
    // rows -> 8 full cache lines, zero partial-line traffic.
    float4 va[L_VIEWS][2];
#pragma unroll
    for (int l = 0; l < L_VIEWS; ++l) {
        va[l][0] = *reinterpret_cast<const float4*>(
            feats + ((size_t)(l * C_CH + cA) * NPIX + nq));
        va[l][1] = *reinterpret_cast<const float4*>(
            feats + ((size_t)(l * C_CH + cB) * NPIX + nq));
    }

    // Partial dots over this thread's 2 channels.
    float d[L_VIEWS][4];
#pragma unroll
    for (int l = 0; l < L_VIEWS; ++l) {
        d[l][0] = va[l][0].x * w0 + va[l][1].x * w1;
        d[l][1] = va[l][0].y * w0 + va[l][1].y * w1;
        d[l][2] = va[l][0].z * w0 + va[l][1].z * w1;
        d[l][3] = va[l][0].w * w0 + va[l][1].w * w1;
    }

    // Butterfly over the 8 channel-groups (lane bits 3..5).
#pragma unroll
    for (int l = 0; l < L_VIEWS; ++l) {
#pragma unroll
        for (int j = 0; j < 4; ++j) {
            d[l][j] += __shfl_xor(d[l][j], 8, 64);
            d[l][j] += __shfl_xor(d[l][j], 16, 64);
            d[l][j] += __shfl_xor(d[l][j], 32, 64);
        }
    }

    // ---- Cross-wave exchange (2.5 KB LDS, one barrier). ----
    __shared__ float4 xl[4][8][L_VIEWS];      // [wave][quad][l] = d[l][0..3]
    if (g == 0) {
#pragma unroll
        for (int l = 0; l < L_VIEWS; ++l) {
            float4 t; t.x = d[l][0]; t.y = d[l][1]; t.z = d[l][2]; t.w = d[l][3];
            xl[h][q][l] = t;
        }
    }
    __syncthreads();

    // Each thread finalizes d only for its own j = g&3 (phase B split 4-way).
    const int jm = g & 3;
    const float* xf = reinterpret_cast<const float*>(xl);
    float dm[L_VIEWS];
#pragma unroll
    for (int l = 0; l < L_VIEWS; ++l) {
        float s = 0.f;
#pragma unroll
        for (int hh = 0; hh < 4; ++hh)
            s += xf[(((hh * 8 + q) * L_VIEWS) + l) * 4 + jm];
        dm[l] = s;
    }

    // ---- Phase B: subset lattice -> shapley -> softmax (one j per thread).
    constexpr float WT1 = -0.6f;          // singleton: -(L-2)/L
    constexpr float WT2 = 0.05f;          // 1!*3!/5!
    constexpr float WT3 = 1.0f / 30.0f;   // 2!*2!/5!
    constexpr float WT4 = 0.05f;          // 3!*1!/5!
    constexpr float WT5 = 0.2f;           // 4!*0!/5!

    float s[32];
    s[0] = bias;                          // fold bias into the lattice root
    float sh[L_VIEWS] = {0.f, 0.f, 0.f, 0.f, 0.f};
#pragma unroll
    for (int m = 1; m < 32; ++m) {
        const int lb  = m & (-m);
        const int lbi = __builtin_ctz(m);
        s[m] = s[m ^ lb] + dm[lbi];
        const float f = fmaxf(s[m], 0.f);
        const int pc = __builtin_popcount(m);
        const float wt = (pc == 1) ? WT1 : (pc == 2) ? WT2
                       : (pc == 3) ? WT3 : (pc == 4) ? WT4 : WT5;
#pragma unroll
        for (int i = 0; i < L_VIEWS; ++i)
            if (m & (1 << i)) sh[i] += wt * f;
    }
    float mx = sh[0];
#pragma unroll
    for (int i = 1; i < L_VIEWS; ++i) mx = fmaxf(mx, sh[i]);
    float e[L_VIEWS];
    float sum = 0.f;
#pragma unroll
    for (int i = 0; i < L_VIEWS; ++i) { e[i] = __expf(sh[i] - mx); sum += e[i]; }
    const float inv = 1.f / sum;
    float attn_mine[L_VIEWS];
#pragma unroll
    for (int i = 0; i < L_VIEWS; ++i) attn_mine[i] = e[i] * inv;

    // Redistribute: attn[l][j] lives at lane q + 8*j (computed for jm==j).
    float attn[L_VIEWS][4];
#pragma unroll
    for (int l = 0; l < L_VIEWS; ++l)
#pragma unroll
        for (int j = 0; j < 4; ++j)
            attn[l][j] = __shfl(attn_mine[l], q + 8 * j, 64);

    // ---- Phase C: fused output straight from registers (no re-read).
    // Store instruction: 8 rows x 128-B full lines, same as loads.
#pragma unroll
    for (int k = 0; k < 2; ++k) {
        const int c = (k == 0) ? cA : cB;
        float4 acc;
        acc.x = va[0][k].x * attn[0][0];
        acc.y = va[0][k].y * attn[0][1];
        acc.z = va[0][k].z * attn[0][2];
        acc.w = va[0][k].w * attn[0][3];
#pragma unroll
        for (int l = 1; l < L_VIEWS; ++l) {
            acc.x += va[l][k].x * attn[l][0];
            acc.y += va[l][k].y * attn[l][1];
            acc.z += va[l][k].z * attn[l][2];
            acc.w += va[l][k].w * attn[l][3];
        }
        *reinterpret_cast<float4*>(out + (size_t)c * NPIX + nq) = acc;
    }
}

extern "C" void kernel_launch(void* const* d_in, const int* in_sizes, int n_in,
                              void* d_out, int out_size, void* d_ws, size_t ws_size,
                              hipStream_t stream) {
    const float* feats = (const float*)d_in[0];   // [5,64,128,256] fp32
    const float* w     = (const float*)d_in[1];   // [64,1] fp32
    const float* b     = (const float*)d_in[2];   // [1] fp32
    float* out         = (float*)d_out;           // [64,128,256] fp32

    // 1024 blocks x 256 threads = 4096 waves; block owns a 32-n (128 B) window.
    shapley_fusion_kernel<<<NPIX / 32, 256, 0, stream>>>(feats, w, b, out);
}